// Round 8
// baseline (347.824 us; speedup 1.0000x reference)
//
#include <hip/hip_runtime.h>
#include <cstdint>
#include <cstddef>

// B=2 S=1024 H=4096 NH=32 NKV=8 HD=128 GROUPS=4
typedef short bf16x8 __attribute__((ext_vector_type(8)));
typedef float f32x4 __attribute__((ext_vector_type(4)));

__device__ __forceinline__ unsigned short f2bf(float f) {
  unsigned int u = __builtin_bit_cast(unsigned int, f);
  u += 0x7fffu + ((u >> 16) & 1u);
  return (unsigned short)(u >> 16);
}

__device__ __forceinline__ void gload_lds(const unsigned short* g, unsigned short* l) {
  __builtin_amdgcn_global_load_lds(
      (const __attribute__((address_space(1))) unsigned int*)g,
      (__attribute__((address_space(3))) unsigned int*)l, 16, 0, 0);
}

// ---- f32 -> bf16 elementwise (x) ----
__global__ void k_convert(const float* __restrict__ in, unsigned short* __restrict__ out, int n4) {
  int i = blockIdx.x * blockDim.x + threadIdx.x;
  if (i >= n4) return;
  float4 v = ((const float4*)in)[i];
  ushort4 o;
  o.x = f2bf(v.x); o.y = f2bf(v.y); o.z = f2bf(v.z); o.w = f2bf(v.w);
  ((ushort4*)out)[i] = o;
}

// ---- transpose + convert: src (K x N) f32 -> dst (N x K) bf16; 64x64 tiles ----
__global__ __launch_bounds__(256) void k_transpose(const float* __restrict__ src,
                                                   unsigned short* __restrict__ dst,
                                                   int K, int N) {
  __shared__ float t[64][65];
  const int n0 = blockIdx.x * 64, k0 = blockIdx.y * 64;
  const int tid = threadIdx.x;
  const int lr = tid >> 4, lc = (tid & 15) * 4;
#pragma unroll
  for (int i = 0; i < 4; ++i) {
    float4 v = *(const float4*)(src + (size_t)(k0 + i * 16 + lr) * N + n0 + lc);
    t[i * 16 + lr][lc] = v.x;
    t[i * 16 + lr][lc + 1] = v.y;
    t[i * 16 + lr][lc + 2] = v.z;
    t[i * 16 + lr][lc + 3] = v.w;
  }
  __syncthreads();
  const int nr = tid >> 3, kk = (tid & 7) * 8;
#pragma unroll
  for (int i = 0; i < 2; ++i) {
    int n = nr + i * 32;
    bf16x8 v;
#pragma unroll
    for (int j = 0; j < 8; ++j) v[j] = (short)f2bf(t[kk + j][n]);
    *(bf16x8*)(dst + (size_t)(n0 + n) * K + k0 + kk) = v;
  }
}

// ---- qkv GEMM, 8-phase 256^2 schedule (T3+T4+T5), fused RoPE/scatter epilogue.
// M=2048, N=6144, K=4096. 512 thr, 8 waves (2Mx4N), BK=64, LDS 128KB (2 dbuf x
// {A,B} x 2 halves x 128x64 bf16). Interleaved frag map: A row = fi*32+wr*16+l16,
// B row = fj*64+wc*16+l16 -> quadrant (mh,nh) touches exactly A-half mh / B-half nh.
// Per phase: 12 ds_read_b128 -> 1 half-tile stage (2 gload_lds, pre-swizzled src,
// linear dest) -> s_barrier -> setprio(1) 16 MFMA setprio(0) -> [vmcnt(4) @ph4/8]
// -> s_barrier. Stage targets are halves dead >=1 barrier ago (liveness-verified).
__global__ __launch_bounds__(512, 2) void k_gemm8p(const unsigned short* __restrict__ A,
                                                   const unsigned short* __restrict__ Bt,
                                                   unsigned short* __restrict__ Qr,
                                                   unsigned short* __restrict__ Kr,
                                                   unsigned short* __restrict__ Vt,
                                                   const float* __restrict__ cosT,
                                                   const float* __restrict__ sinT) {
  __shared__ __align__(16) unsigned short lds[2][2][2][128 * 64]; // [buf][A/B][half][.]
  const int tid = threadIdx.x;
  const int lane = tid & 63, wv = tid >> 6;
  const int wr = wv >> 2, wc = wv & 3;
  const int l16 = lane & 15, lhi = lane >> 4;
  // T1 swizzle: 192 blocks, XCD = lid%8 -> contiguous 8x3 tile rect per XCD
  const int lid = blockIdx.x;
  const int swz = (lid & 7) * 24 + (lid >> 3);
  const int bm2 = (swz & 7) * 256, bn2 = (swz >> 3) * 256;

  f32x4 acc[8][4] = {};

  auto STAGE = [&](int buf, int mat, int half, const unsigned short* srcM, int srcRowBase, int kt) {
#pragma unroll
    for (int j = 0; j < 2; ++j) {
      int row = j * 64 + wv * 8 + (lane >> 3);
      int chunk = (lane & 7) ^ (row & 7); // pre-swizzled source; linear LDS dest
      gload_lds(srcM + (size_t)(srcRowBase + row) * 4096 + kt * 64 + chunk * 8,
                &lds[buf][mat][half][(j * 512 + wv * 64) * 8]);
    }
  };

  auto PHASE = [&](int buf, int mh, int nh, int stg, int b2, int m2, int h2,
                   const unsigned short* s2, int rb2, int kt2, int vm) {
    bf16x8 af[4][2], bfr[2][2];
#pragma unroll
    for (int fl = 0; fl < 4; ++fl) {
      int ra = fl * 32 + wr * 16 + l16;
#pragma unroll
      for (int s = 0; s < 2; ++s)
        af[fl][s] = *(const bf16x8*)&lds[buf][0][mh][ra * 64 + (((s * 4 + lhi) ^ (ra & 7)) * 8)];
    }
#pragma unroll
    for (int fl = 0; fl < 2; ++fl) {
      int rb = fl * 64 + wc * 16 + l16;
#pragma unroll
      for (int s = 0; s < 2; ++s)
        bfr[fl][s] = *(const bf16x8*)&lds[buf][1][nh][rb * 64 + (((s * 4 + lhi) ^ (rb & 7)) * 8)];
    }
    if (stg) STAGE(b2, m2, h2, s2, rb2, kt2);
    __builtin_amdgcn_s_barrier();
    __builtin_amdgcn_s_setprio(1);
#pragma unroll
    for (int fl = 0; fl < 4; ++fl)
#pragma unroll
      for (int gl = 0; gl < 2; ++gl)
#pragma unroll
        for (int s = 0; s < 2; ++s)
          acc[mh * 4 + fl][nh * 2 + gl] =
              __builtin_amdgcn_mfma_f32_16x16x32_bf16(af[fl][s], bfr[gl][s],
                                                      acc[mh * 4 + fl][nh * 2 + gl], 0, 0, 0);
    __builtin_amdgcn_s_setprio(0);
    if (vm == 4) {
      asm volatile("s_waitcnt vmcnt(4)" ::: "memory");
      __builtin_amdgcn_sched_barrier(0);
    } else if (vm == 0) {
      asm volatile("s_waitcnt vmcnt(0)" ::: "memory");
      __builtin_amdgcn_sched_barrier(0);
    }
    __builtin_amdgcn_s_barrier();
  };

  // prologue: tile0 -> buf0, tile1 -> buf1 (16 loads); wait tile0 (own oldest 8)
  STAGE(0, 0, 0, A, bm2, 0);       STAGE(0, 0, 1, A, bm2 + 128, 0);
  STAGE(0, 1, 0, Bt, bn2, 0);      STAGE(0, 1, 1, Bt, bn2 + 128, 0);
  STAGE(1, 0, 0, A, bm2, 1);       STAGE(1, 0, 1, A, bm2 + 128, 1);
  STAGE(1, 1, 0, Bt, bn2, 1);      STAGE(1, 1, 1, Bt, bn2 + 128, 1);
  asm volatile("s_waitcnt vmcnt(8)" ::: "memory");
  __builtin_amdgcn_sched_barrier(0);
  __builtin_amdgcn_s_barrier();

  for (int i = 0; i < 32; ++i) {
    const int t1 = 2 * i + 1, t2 = 2 * i + 2, t3 = 2 * i + 3;
    const int nf = (i > 0), nl = (i < 31);
    // ph1: buf0 q(0,0); stage buf1.A0 <- t1   (buf1.A0 dead since prev ph8)
    PHASE(0, 0, 0, nf, 1, 0, 0, A, bm2, t1, -1);
    // ph2: buf0 q(1,0); stage buf1.B1 <- t1
    PHASE(0, 1, 0, nf, 1, 1, 1, Bt, bn2 + 128, t1, -1);
    // ph3: buf0 q(1,1); stage buf0.B0 <- t2   (B0 dead after ph2)
    PHASE(0, 1, 1, nl, 0, 1, 0, Bt, bn2, t2, -1);
    // ph4: buf0 q(0,1); stage buf0.A1 <- t2; vmcnt: tile t1 landed
    PHASE(0, 0, 1, nl, 0, 0, 1, A, bm2 + 128, t2, nl ? 4 : 0);
    // ph5: buf1 q(0,0); stage buf0.A0 <- t2
    PHASE(1, 0, 0, nl, 0, 0, 0, A, bm2, t2, -1);
    // ph6: buf1 q(1,0); stage buf0.B1 <- t2
    PHASE(1, 1, 0, nl, 0, 1, 1, Bt, bn2 + 128, t2, -1);
    // ph7: buf1 q(1,1); stage buf1.B0 <- t3
    PHASE(1, 1, 1, nl, 1, 1, 0, Bt, bn2, t3, -1);
    // ph8: buf1 q(0,1); stage buf1.A1 <- t3; vmcnt: tile t2 landed
    PHASE(1, 0, 1, nl, 1, 0, 1, A, bm2 + 128, t3, nl ? 4 : -1);
  }

  // epilogue: fused RoPE + Q/K/V scatter. row = bm2+fi*32+wr*16+lhi*4+r,
  // col = bn2+fj*64+wc*16+l16. cols [0,4096)=Q rope, [4096,5120)=K rope,
  // [5120,6144)=V transpose scatter.
#pragma unroll
  for (int fi = 0; fi < 8; ++fi) {
    int rbase = bm2 + fi * 32 + wr * 16 + lhi * 4;
    int b = rbase >> 10, sbase = rbase & 1023;
#pragma unroll
    for (int fj = 0; fj < 4; ++fj) {
      int col = bn2 + fj * 64 + wc * 16 + l16;
      if (col < 5120) {
        int ip = (col & 127) >> 1;
        float sgn = (col & 1) ? 1.0f : -1.0f;
        unsigned short* dst;
        if (col < 4096)
          dst = Qr + ((size_t)(b * 32 + (col >> 7)) * 1024) * 128 + (col & 127);
        else
          dst = Kr + ((size_t)(b * 8 + ((col - 4096) >> 7)) * 1024) * 128 + (col & 127);
#pragma unroll
        for (int r = 0; r < 4; ++r) {
          float own = acc[fi][fj][r];
          float other = __shfl_xor(own, 1);
          int s = sbase + r;
          float c = cosT[s * 64 + ip], sn = sinT[s * 64 + ip];
          dst[(size_t)s * 128] = f2bf(own * c + sgn * other * sn);
        }
      } else {
        int kvh = (col - 5120) >> 7, d = col & 127;
        unsigned short* dst = Vt + ((size_t)(b * 8 + kvh) * 128 + d) * 1024;
#pragma unroll
        for (int r = 0; r < 4; ++r) dst[sbase + r] = f2bf(acc[fi][fj][r]);
      }
    }
  }
}

// ---- out-proj GEMM: 128^2 reg-staged structure (round-5, 827 TF) + T1 swizzle ----
__global__ __launch_bounds__(256) void k_gemm(const unsigned short* __restrict__ A,
                                              const unsigned short* __restrict__ Bt,
                                              float* __restrict__ C, int M, int N, int K) {
  __shared__ __align__(16) unsigned short lA[128 * 64];
  __shared__ __align__(16) unsigned short lB[128 * 64];
  const int tid = threadIdx.x;
  const int lane = tid & 63, wv = tid >> 6;
  const int wr = wv >> 1, wc = wv & 1;
  const int lid = blockIdx.y * gridDim.x + blockIdx.x;
  const int cpx = (gridDim.x * gridDim.y) >> 3;
  const int swz = (lid & 7) * cpx + (lid >> 3);
  const int bm = (swz % gridDim.x) * 128, bn = (swz / gridDim.x) * 128;
  const int l16 = lane & 15, lhi = lane >> 4;
  f32x4 acc[4][4] = {};
  bf16x8 ar[4], br[4];

#pragma unroll
  for (int i = 0; i < 4; ++i) {
    int c = tid + i * 256, row = c >> 3, c16 = c & 7;
    ar[i] = *(const bf16x8*)(A + (size_t)(bm + row) * K + 0 + c16 * 8);
    br[i] = *(const bf16x8*)(Bt + (size_t)(bn + row) * K + 0 + c16 * 8);
  }
  const int nkt = K >> 6;
  for (int kt = 0; kt < nkt; ++kt) {
    __syncthreads();
#pragma unroll
    for (int i = 0; i < 4; ++i) {
      int c = tid + i * 256, row = c >> 3, c16 = c & 7;
      int pc = c16 ^ (row & 7);
      *(bf16x8*)((char*)lA + row * 128 + pc * 16) = ar[i];
      *(bf16x8*)((char*)lB + row * 128 + pc * 16) = br[i];
    }
    __syncthreads();
    if (kt + 1 < nkt) {
      int kofs = (kt + 1) << 6;
#pragma unroll
      for (int i = 0; i < 4; ++i) {
        int c = tid + i * 256, row = c >> 3, c16 = c & 7;
        ar[i] = *(const bf16x8*)(A + (size_t)(bm + row) * K + kofs + c16 * 8);
        br[i] = *(const bf16x8*)(Bt + (size_t)(bn + row) * K + kofs + c16 * 8);
      }
    }
#pragma unroll
    for (int s = 0; s < 2; ++s) {
      bf16x8 af[4], bfr[4];
#pragma unroll
      for (int f = 0; f < 4; ++f) {
        int rowa = wr * 64 + f * 16 + l16;
        int ca = (s * 4 + lhi) ^ (rowa & 7);
        af[f] = *(const bf16x8*)((char*)lA + rowa * 128 + ca * 16);
        int rowb = wc * 64 + f * 16 + l16;
        int cb = (s * 4 + lhi) ^ (rowb & 7);
        bfr[f] = *(const bf16x8*)((char*)lB + rowb * 128 + cb * 16);
      }
#pragma unroll
      for (int fi = 0; fi < 4; ++fi)
#pragma unroll
        for (int fj = 0; fj < 4; ++fj)
          acc[fi][fj] = __builtin_amdgcn_mfma_f32_16x16x32_bf16(af[fi], bfr[fj], acc[fi][fj], 0, 0, 0);
    }
  }
#pragma unroll
  for (int fi = 0; fi < 4; ++fi) {
    int rbase = bm + wr * 64 + fi * 16 + lhi * 4;
#pragma unroll
    for (int fj = 0; fj < 4; ++fj) {
      int col = bn + wc * 64 + fj * 16 + l16;
#pragma unroll
      for (int r = 0; r < 4; ++r)
        C[(size_t)(rbase + r) * N + col] = acc[fi][fj][r];
    }
  }
}

// ---- flash attention (round-5 structure, T14) ----
__global__ __launch_bounds__(256) void k_attn(const unsigned short* __restrict__ Qr,
                                              const unsigned short* __restrict__ Kr,
                                              const unsigned short* __restrict__ Vt,
                                              unsigned short* __restrict__ Out) {
  __shared__ __align__(16) unsigned short lK[64 * 128];
  __shared__ __align__(16) unsigned short lV[128 * 64];
  __shared__ __align__(16) unsigned short lP[4 * 16 * 64];
  const int tid = threadIdx.x, lane = tid & 63, wv = tid >> 6;
  const int qt = blockIdx.x, h = blockIdx.y, b = blockIdx.z;
  const int kvh = h >> 2;
  const int q0 = qt * 64;
  const int l16 = lane & 15, lhi = lane >> 4;

  const unsigned short* Qbase = Qr + ((size_t)(b * 32 + h) * 1024 + q0 + wv * 16 + l16) * 128;
  bf16x8 qf[4];
#pragma unroll
  for (int s = 0; s < 4; ++s) qf[s] = *(const bf16x8*)(Qbase + s * 32 + lhi * 8);

  const unsigned short* Kbase = Kr + (size_t)(b * 8 + kvh) * 1024 * 128;
  const unsigned short* Vbase = Vt + (size_t)(b * 8 + kvh) * 128 * 1024;

  f32x4 oacc[8] = {};
  float mrow[4] = {-1e30f, -1e30f, -1e30f, -1e30f};
  float lrow[4] = {0.f, 0.f, 0.f, 0.f};
  const int ntk = qt + 1;
  bf16x8 kreg[4], vreg[4];

#pragma unroll
  for (int i = 0; i < 4; ++i) {
    int c = tid + i * 256;
    int krow = c >> 4, kc = c & 15;
    kreg[i] = *(const bf16x8*)(Kbase + (size_t)krow * 128 + kc * 8);
    int vrow = c >> 3, vc = c & 7;
    vreg[i] = *(const bf16x8*)(Vbase + (size_t)vrow * 1024 + vc * 8);
  }

  for (int kt = 0; kt < ntk; ++kt) {
    const int k0 = kt * 64;
    __syncthreads();
#pragma unroll
    for (int i = 0; i < 4; ++i) {
      int c = tid + i * 256;
      int krow = c >> 4, kc = c & 15;
      *(bf16x8*)((char*)lK + krow * 256 + (kc ^ (krow & 7)) * 16) = kreg[i];
      int vrow = c >> 3, vc = c & 7;
      *(bf16x8*)((char*)lV + vrow * 128 + (vc ^ (vrow & 7)) * 16) = vreg[i];
    }
    __syncthreads();

    if (kt + 1 < ntk) {
      const int kn = (kt + 1) * 64;
#pragma unroll
      for (int i = 0; i < 4; ++i) {
        int c = tid + i * 256;
        int krow = c >> 4, kc = c & 15;
        kreg[i] = *(const bf16x8*)(Kbase + (size_t)(kn + krow) * 128 + kc * 8);
        int vrow = c >> 3, vc = c & 7;
        vreg[i] = *(const bf16x8*)(Vbase + (size_t)vrow * 1024 + kn + vc * 8);
      }
    }

    f32x4 sacc[4] = {};
#pragma unroll
    for (int kf = 0; kf < 4; ++kf) {
      int rowk = kf * 16 + l16;
#pragma unroll
      for (int s = 0; s < 4; ++s) {
        int ck = (s * 4 + lhi) ^ (rowk & 7);
        bf16x8 kfr = *(const bf16x8*)((char*)lK + rowk * 256 + ck * 16);
        sacc[kf] = __builtin_amdgcn_mfma_f32_16x16x32_bf16(qf[s], kfr, sacc[kf], 0, 0, 0);
      }
    }

    const int qg = q0 + wv * 16 + lhi * 4;
    float mt[4] = {-1e30f, -1e30f, -1e30f, -1e30f};
#pragma unroll
    for (int kf = 0; kf < 4; ++kf) {
      int kg = k0 + kf * 16 + l16;
#pragma unroll
      for (int r = 0; r < 4; ++r) {
        float v = sacc[kf][r] * 0.08838834764831845f;
        v = (kg <= qg + r) ? v : -1e9f;
        sacc[kf][r] = v;
        mt[r] = fmaxf(mt[r], v);
      }
    }
#pragma unroll
    for (int r = 0; r < 4; ++r) {
#pragma unroll
      for (int off = 1; off < 16; off <<= 1) mt[r] = fmaxf(mt[r], __shfl_xor(mt[r], off));
    }
    float alpha[4], rs[4];
#pragma unroll
    for (int r = 0; r < 4; ++r) {
      float mn = fmaxf(mrow[r], mt[r]);
      alpha[r] = __expf(mrow[r] - mn);
      mrow[r] = mn;
      rs[r] = 0.f;
    }
#pragma unroll
    for (int kf = 0; kf < 4; ++kf) {
      int key = kf * 16 + l16;
#pragma unroll
      for (int r = 0; r < 4; ++r) {
        float p = __expf(sacc[kf][r] - mrow[r]);
        rs[r] += p;
        int prow = lhi * 4 + r;
        int addr = wv * 2048 + ((prow * 128 + key * 2) ^ ((prow & 7) << 4));
        *(unsigned short*)((char*)lP + addr) = f2bf(p);
      }
    }
#pragma unroll
    for (int r = 0; r < 4; ++r) {
#pragma unroll
      for (int off = 1; off < 16; off <<= 1) rs[r] += __shfl_xor(rs[r], off);
      lrow[r] = lrow[r] * alpha[r] + rs[r];
    }
#pragma unroll
    for (int nf = 0; nf < 8; ++nf)
#pragma unroll
      for (int r = 0; r < 4; ++r) oacc[nf][r] *= alpha[r];

#pragma unroll
    for (int s2 = 0; s2 < 2; ++s2) {
      int prow = l16;
      int paddr = wv * 2048 + ((prow * 128 + s2 * 64 + lhi * 16) ^ ((prow & 7) << 4));
      bf16x8 pa = *(const bf16x8*)((char*)lP + paddr);
#pragma unroll
      for (int nf = 0; nf < 8; ++nf) {
        int rowd = nf * 16 + l16;
        int cv = (s2 * 4 + lhi) ^ (rowd & 7);
        bf16x8 vfr = *(const bf16x8*)((char*)lV + rowd * 128 + cv * 16);
        oacc[nf] = __builtin_amdgcn_mfma_f32_16x16x32_bf16(pa, vfr, oacc[nf], 0, 0, 0);
      }
    }
  }

  unsigned short* Ob = Out + ((size_t)(b * 1024) + q0 + wv * 16 + lhi * 4) * 4096 + h * 128;
#pragma unroll
  for (int r = 0; r < 4; ++r) {
    float inv = 1.f / lrow[r];
#pragma unroll
    for (int nf = 0; nf < 8; ++nf)
      Ob[(size_t)r * 4096 + nf * 16 + l16] = f2bf(oacc[nf][r] * inv);
  }
}

extern "C" void kernel_launch(void* const* d_in, const int* in_sizes, int n_in,
                              void* d_out, int out_size, void* d_ws, size_t ws_size,
                              hipStream_t stream) {
  const float* x = (const float*)d_in[0];
  const float* w_qkv = (const float*)d_in[1];
  const float* w_o = (const float*)d_in[2];
  const float* cosT = (const float*)d_in[3];
  const float* sinT = (const float*)d_in[4];

  char* ws = (char*)d_ws;
  unsigned short* wqkv_t = (unsigned short*)(ws);                 // 6144x4096 bf16
  unsigned short* wo_t   = (unsigned short*)(ws + 50331648);      // 4096x4096 bf16
  unsigned short* xb     = (unsigned short*)(ws + 83886080);      // 2048x4096 bf16
  unsigned short* Qr     = (unsigned short*)(ws + 100663296);     // 2*32*1024*128 bf16
  unsigned short* Kr     = (unsigned short*)(ws + 117440512);     // 2*8*1024*128 bf16
  unsigned short* Vt     = (unsigned short*)(ws + 121634816);     // 2*8*128*1024 bf16
  unsigned short* attn   = (unsigned short*)(ws + 125829120);     // 2048x4096 bf16

  k_convert<<<8192, 256, 0, stream>>>(x, xb, 2048 * 4096 / 4);
  k_transpose<<<dim3(6144 / 64, 4096 / 64), 256, 0, stream>>>(w_qkv, wqkv_t, 4096, 6144);
  k_transpose<<<dim3(4096 / 64, 4096 / 64), 256, 0, stream>>>(w_o, wo_t, 4096, 4096);
  k_gemm8p<<<192, 512, 0, stream>>>(xb, wqkv_t, Qr, Kr, Vt, cosT, sinT);
  k_attn<<<dim3(16, 32, 2), 256, 0, stream>>>(Qr, Kr, Vt, attn);
  k_gemm<<<dim3(16, 32), 256, 0, stream>>>(attn, wo_t, (float*)d_out, 2048, 4096, 4096);
}

// Round 9
// 333.603 us; speedup vs baseline: 1.0426x; 1.0426x over previous
//
#include <hip/hip_runtime.h>
#include <cstdint>
#include <cstddef>

// B=2 S=1024 H=4096 NH=32 NKV=8 HD=128 GROUPS=4
typedef short bf16x8 __attribute__((ext_vector_type(8)));
typedef float f32x4 __attribute__((ext_vector_type(4)));

__device__ __forceinline__ unsigned short f2bf(float f) {
  unsigned int u = __builtin_bit_cast(unsigned int, f);
  u += 0x7fffu + ((u >> 16) & 1u);
  return (unsigned short)(u >> 16);
}

// ---- transpose tile helper: 64x64, float4 loads / bf16x8 stores ----
__device__ __forceinline__ void transpose_tile(const float* __restrict__ src,
                                               unsigned short* __restrict__ dst,
                                               int K, int N, int n0, int k0, int tid) {
  __shared__ float t[64][65];
  const int lr = tid >> 4, lc = (tid & 15) * 4;
#pragma unroll
  for (int i = 0; i < 4; ++i) {
    float4 v = *(const float4*)(src + (size_t)(k0 + i * 16 + lr) * N + n0 + lc);
    t[i * 16 + lr][lc] = v.x;
    t[i * 16 + lr][lc + 1] = v.y;
    t[i * 16 + lr][lc + 2] = v.z;
    t[i * 16 + lr][lc + 3] = v.w;
  }
  __syncthreads();
  const int nr = tid >> 3, kk = (tid & 7) * 8;
#pragma unroll
  for (int i = 0; i < 2; ++i) {
    int n = nr + i * 32;
    bf16x8 v;
#pragma unroll
    for (int j = 0; j < 8; ++j) v[j] = (short)f2bf(t[kk + j][n]);
    *(bf16x8*)(dst + (size_t)(n0 + n) * K + k0 + kk) = v;
  }
}

// ---- fused prep: x convert (blocks [0,8192)), w_qkv transpose [8192,14336),
// w_o transpose [14336,18432). Whole blocks take one path (no divergence). ----
__global__ __launch_bounds__(256) void k_prep(const float* __restrict__ x,
                                              const float* __restrict__ w_qkv,
                                              const float* __restrict__ w_o,
                                              unsigned short* __restrict__ xb,
                                              unsigned short* __restrict__ wqkv_t,
                                              unsigned short* __restrict__ wo_t) {
  const int bid = blockIdx.x, tid = threadIdx.x;
  if (bid < 8192) {
    int i = bid * 256 + tid;
    float4 v = ((const float4*)x)[i];
    ushort4 o;
    o.x = f2bf(v.x); o.y = f2bf(v.y); o.z = f2bf(v.z); o.w = f2bf(v.w);
    ((ushort4*)xb)[i] = o;
  } else if (bid < 14336) {
    int t = bid - 8192;
    transpose_tile(w_qkv, wqkv_t, 4096, 6144, (t % 96) * 64, (t / 96) * 64, tid);
  } else {
    int t = bid - 14336;
    transpose_tile(w_o, wo_t, 4096, 4096, (t & 63) * 64, (t >> 6) * 64, tid);
  }
}

// ---- GEMM: A[M,K]bf16 @ Bt[N,K]bf16^T ; BM=BN=128, BK=64, 4 waves.
// Reg-staged, XOR-swizzled ds_write, prefetch issued after the barrier
// (flies under MFMA). T1 XCD-aware block swizzle.
// MODE 0: C[M,N] f32.  MODE 1: fused RoPE + Q/K/V scatter epilogue (qkv proj).
template <int MODE>
__global__ __launch_bounds__(256) void k_gemm(const unsigned short* __restrict__ A,
                                              const unsigned short* __restrict__ Bt,
                                              float* __restrict__ C,
                                              unsigned short* __restrict__ Qr,
                                              unsigned short* __restrict__ Kr,
                                              unsigned short* __restrict__ Vt,
                                              const float* __restrict__ cosT,
                                              const float* __restrict__ sinT,
                                              int M, int N, int K) {
  __shared__ __align__(16) unsigned short lA[128 * 64];
  __shared__ __align__(16) unsigned short lB[128 * 64];
  const int tid = threadIdx.x;
  const int lane = tid & 63, wv = tid >> 6;
  const int wr = wv >> 1, wc = wv & 1;
  const int lid = blockIdx.y * gridDim.x + blockIdx.x;
  const int cpx = (gridDim.x * gridDim.y) >> 3;
  const int swz = (lid & 7) * cpx + (lid >> 3);
  const int bm = (swz % gridDim.x) * 128, bn = (swz / gridDim.x) * 128;
  const int l16 = lane & 15, lhi = lane >> 4;
  f32x4 acc[4][4] = {};
  bf16x8 ar[4], br[4];

#pragma unroll
  for (int i = 0; i < 4; ++i) {
    int c = tid + i * 256, row = c >> 3, c16 = c & 7;
    ar[i] = *(const bf16x8*)(A + (size_t)(bm + row) * K + 0 + c16 * 8);
    br[i] = *(const bf16x8*)(Bt + (size_t)(bn + row) * K + 0 + c16 * 8);
  }
  const int nkt = K >> 6;
  for (int kt = 0; kt < nkt; ++kt) {
    __syncthreads();
#pragma unroll
    for (int i = 0; i < 4; ++i) {
      int c = tid + i * 256, row = c >> 3, c16 = c & 7;
      int pc = c16 ^ (row & 7);
      *(bf16x8*)((char*)lA + row * 128 + pc * 16) = ar[i];
      *(bf16x8*)((char*)lB + row * 128 + pc * 16) = br[i];
    }
    __syncthreads();
    if (kt + 1 < nkt) {
      int kofs = (kt + 1) << 6;
#pragma unroll
      for (int i = 0; i < 4; ++i) {
        int c = tid + i * 256, row = c >> 3, c16 = c & 7;
        ar[i] = *(const bf16x8*)(A + (size_t)(bm + row) * K + kofs + c16 * 8);
        br[i] = *(const bf16x8*)(Bt + (size_t)(bn + row) * K + kofs + c16 * 8);
      }
    }
#pragma unroll
    for (int s = 0; s < 2; ++s) {
      bf16x8 af[4], bfr[4];
#pragma unroll
      for (int f = 0; f < 4; ++f) {
        int rowa = wr * 64 + f * 16 + l16;
        int ca = (s * 4 + lhi) ^ (rowa & 7);
        af[f] = *(const bf16x8*)((char*)lA + rowa * 128 + ca * 16);
        int rowb = wc * 64 + f * 16 + l16;
        int cb = (s * 4 + lhi) ^ (rowb & 7);
        bfr[f] = *(const bf16x8*)((char*)lB + rowb * 128 + cb * 16);
      }
#pragma unroll
      for (int fi = 0; fi < 4; ++fi)
#pragma unroll
        for (int fj = 0; fj < 4; ++fj)
          acc[fi][fj] = __builtin_amdgcn_mfma_f32_16x16x32_bf16(af[fi], bfr[fj], acc[fi][fj], 0, 0, 0);
    }
  }

  if (MODE == 0) {
#pragma unroll
    for (int fi = 0; fi < 4; ++fi) {
      int rbase = bm + wr * 64 + fi * 16 + lhi * 4;
#pragma unroll
      for (int fj = 0; fj < 4; ++fj) {
        int col = bn + wc * 64 + fj * 16 + l16;
#pragma unroll
        for (int r = 0; r < 4; ++r)
          C[(size_t)(rbase + r) * N + col] = acc[fi][fj][r];
      }
    }
  } else {
#pragma unroll
    for (int fi = 0; fi < 4; ++fi) {
      int rbase = bm + wr * 64 + fi * 16 + lhi * 4;
      int b = rbase >> 10, sbase = rbase & 1023;
#pragma unroll
      for (int fj = 0; fj < 4; ++fj) {
        int col = bn + wc * 64 + fj * 16 + l16;
        if (col < 5120) {
          int i = (col & 127) >> 1;
          float sgn = (col & 1) ? 1.0f : -1.0f;
          unsigned short* dst;
          if (col < 4096)
            dst = Qr + ((size_t)(b * 32 + (col >> 7)) * 1024) * 128 + (col & 127);
          else
            dst = Kr + ((size_t)(b * 8 + ((col - 4096) >> 7)) * 1024) * 128 + (col & 127);
#pragma unroll
          for (int r = 0; r < 4; ++r) {
            float own = acc[fi][fj][r];
            float other = __shfl_xor(own, 1);
            int s = sbase + r;
            float c = cosT[s * 64 + i], sn = sinT[s * 64 + i];
            dst[(size_t)s * 128] = f2bf(own * c + sgn * other * sn);
          }
        } else {
          int kvh = (col - 5120) >> 7, d = col & 127;
          unsigned short* dst = Vt + ((size_t)(b * 8 + kvh) * 128 + d) * 1024;
#pragma unroll
          for (int r = 0; r < 4; ++r) dst[sbase + r] = f2bf(acc[fi][fj][r]);
        }
      }
    }
  }
}

// ---- flash attention: 1 block = (qtile of 128, h, b); 4 waves x 32 q-rows
// (2 row-groups of 16). K/V staged once per tile, shared by both row-groups ->
// half the staging/barrier work of QBLK=64. T14 post-barrier prefetch. ----
__global__ __launch_bounds__(256, 2) void k_attn(const unsigned short* __restrict__ Qr,
                                                 const unsigned short* __restrict__ Kr,
                                                 const unsigned short* __restrict__ Vt,
                                                 unsigned short* __restrict__ Out) {
  __shared__ __align__(16) unsigned short lK[64 * 128];
  __shared__ __align__(16) unsigned short lV[128 * 64];
  __shared__ __align__(16) unsigned short lP[4 * 32 * 64];
  const int tid = threadIdx.x, lane = tid & 63, wv = tid >> 6;
  const int qtb = blockIdx.x, h = blockIdx.y, b = blockIdx.z;
  const int kvh = h >> 2;
  const int q0 = qtb * 128;
  const int l16 = lane & 15, lhi = lane >> 4;

  bf16x8 qf[2][4];
#pragma unroll
  for (int g = 0; g < 2; ++g) {
    const unsigned short* Qb =
        Qr + ((size_t)(b * 32 + h) * 1024 + q0 + wv * 32 + g * 16 + l16) * 128;
#pragma unroll
    for (int s = 0; s < 4; ++s) qf[g][s] = *(const bf16x8*)(Qb + s * 32 + lhi * 8);
  }

  const unsigned short* Kbase = Kr + (size_t)(b * 8 + kvh) * 1024 * 128;
  const unsigned short* Vbase = Vt + (size_t)(b * 8 + kvh) * 128 * 1024;

  f32x4 oacc[2][8] = {};
  float mrow[2][4], lrow[2][4];
#pragma unroll
  for (int g = 0; g < 2; ++g)
#pragma unroll
    for (int r = 0; r < 4; ++r) { mrow[g][r] = -1e30f; lrow[g][r] = 0.f; }
  const int ntk = 2 * qtb + 2;
  bf16x8 kreg[4], vreg[4];

#pragma unroll
  for (int i = 0; i < 4; ++i) {
    int c = tid + i * 256;
    int krow = c >> 4, kc = c & 15;
    kreg[i] = *(const bf16x8*)(Kbase + (size_t)krow * 128 + kc * 8);
    int vrow = c >> 3, vc = c & 7;
    vreg[i] = *(const bf16x8*)(Vbase + (size_t)vrow * 1024 + vc * 8);
  }

  for (int kt = 0; kt < ntk; ++kt) {
    const int k0 = kt * 64;
    __syncthreads();
#pragma unroll
    for (int i = 0; i < 4; ++i) {
      int c = tid + i * 256;
      int krow = c >> 4, kc = c & 15;
      *(bf16x8*)((char*)lK + krow * 256 + (kc ^ (krow & 7)) * 16) = kreg[i];
      int vrow = c >> 3, vc = c & 7;
      *(bf16x8*)((char*)lV + vrow * 128 + (vc ^ (vrow & 7)) * 16) = vreg[i];
    }
    __syncthreads();

    if (kt + 1 < ntk) {
      const int kn = (kt + 1) * 64;
#pragma unroll
      for (int i = 0; i < 4; ++i) {
        int c = tid + i * 256;
        int krow = c >> 4, kc = c & 15;
        kreg[i] = *(const bf16x8*)(Kbase + (size_t)(kn + krow) * 128 + kc * 8);
        int vrow = c >> 3, vc = c & 7;
        vreg[i] = *(const bf16x8*)(Vbase + (size_t)vrow * 1024 + kn + vc * 8);
      }
    }

    // QK^T: K-frags loaded once, used by both row-groups
    f32x4 sacc[2][4] = {};
#pragma unroll
    for (int kf = 0; kf < 4; ++kf) {
      int rowk = kf * 16 + l16;
#pragma unroll
      for (int s = 0; s < 4; ++s) {
        int ck = (s * 4 + lhi) ^ (rowk & 7);
        bf16x8 kfr = *(const bf16x8*)((char*)lK + rowk * 256 + ck * 16);
        sacc[0][kf] = __builtin_amdgcn_mfma_f32_16x16x32_bf16(qf[0][s], kfr, sacc[0][kf], 0, 0, 0);
        sacc[1][kf] = __builtin_amdgcn_mfma_f32_16x16x32_bf16(qf[1][s], kfr, sacc[1][kf], 0, 0, 0);
      }
    }

    float alpha[2][4];
#pragma unroll
    for (int g = 0; g < 2; ++g) {
      const int qg = q0 + wv * 32 + g * 16 + lhi * 4;
      float mt[4] = {-1e30f, -1e30f, -1e30f, -1e30f};
#pragma unroll
      for (int kf = 0; kf < 4; ++kf) {
        int kg = k0 + kf * 16 + l16;
#pragma unroll
        for (int r = 0; r < 4; ++r) {
          float v = sacc[g][kf][r] * 0.08838834764831845f;
          v = (kg <= qg + r) ? v : -1e9f;
          sacc[g][kf][r] = v;
          mt[r] = fmaxf(mt[r], v);
        }
      }
#pragma unroll
      for (int r = 0; r < 4; ++r) {
#pragma unroll
        for (int off = 1; off < 16; off <<= 1) mt[r] = fmaxf(mt[r], __shfl_xor(mt[r], off));
      }
      float rs[4];
#pragma unroll
      for (int r = 0; r < 4; ++r) {
        float mn = fmaxf(mrow[g][r], mt[r]);
        alpha[g][r] = __expf(mrow[g][r] - mn);
        mrow[g][r] = mn;
        rs[r] = 0.f;
      }
#pragma unroll
      for (int kf = 0; kf < 4; ++kf) {
        int key = kf * 16 + l16;
#pragma unroll
        for (int r = 0; r < 4; ++r) {
          float p = __expf(sacc[g][kf][r] - mrow[g][r]);
          rs[r] += p;
          int prow = g * 16 + lhi * 4 + r;
          int addr = wv * 4096 + ((prow * 128 + key * 2) ^ ((prow & 7) << 4));
          *(unsigned short*)((char*)lP + addr) = f2bf(p);
        }
      }
#pragma unroll
      for (int r = 0; r < 4; ++r) {
#pragma unroll
        for (int off = 1; off < 16; off <<= 1) rs[r] += __shfl_xor(rs[r], off);
        lrow[g][r] = lrow[g][r] * alpha[g][r] + rs[r];
      }
#pragma unroll
      for (int nf = 0; nf < 8; ++nf)
#pragma unroll
        for (int r = 0; r < 4; ++r) oacc[g][nf][r] *= alpha[g][r];
    }

    // PV: V-frags loaded once, used by both row-groups
#pragma unroll
    for (int s2 = 0; s2 < 2; ++s2) {
      bf16x8 pa[2];
#pragma unroll
      for (int g = 0; g < 2; ++g) {
        int prow = g * 16 + l16;
        int paddr = wv * 4096 + ((prow * 128 + s2 * 64 + lhi * 16) ^ ((prow & 7) << 4));
        pa[g] = *(const bf16x8*)((char*)lP + paddr);
      }
#pragma unroll
      for (int nf = 0; nf < 8; ++nf) {
        int rowd = nf * 16 + l16;
        int cv = (s2 * 4 + lhi) ^ (rowd & 7);
        bf16x8 vfr = *(const bf16x8*)((char*)lV + rowd * 128 + cv * 16);
        oacc[0][nf] = __builtin_amdgcn_mfma_f32_16x16x32_bf16(pa[0], vfr, oacc[0][nf], 0, 0, 0);
        oacc[1][nf] = __builtin_amdgcn_mfma_f32_16x16x32_bf16(pa[1], vfr, oacc[1][nf], 0, 0, 0);
      }
    }
  }

#pragma unroll
  for (int g = 0; g < 2; ++g) {
    unsigned short* Ob =
        Out + ((size_t)(b * 1024) + q0 + wv * 32 + g * 16 + lhi * 4) * 4096 + h * 128;
#pragma unroll
    for (int r = 0; r < 4; ++r) {
      float inv = 1.f / lrow[g][r];
#pragma unroll
      for (int nf = 0; nf < 8; ++nf)
        Ob[(size_t)r * 4096 + nf * 16 + l16] = f2bf(oacc[g][nf][r] * inv);
    }
  }
}

extern "C" void kernel_launch(void* const* d_in, const int* in_sizes, int n_in,
                              void* d_out, int out_size, void* d_ws, size_t ws_size,
                              hipStream_t stream) {
  const float* x = (const float*)d_in[0];
  const float* w_qkv = (const float*)d_in[1];
  const float* w_o = (const float*)d_in[2];
  const float* cosT = (const float*)d_in[3];
  const float* sinT = (const float*)d_in[4];

  char* ws = (char*)d_ws;
  unsigned short* wqkv_t = (unsigned short*)(ws);                 // 6144x4096 bf16
  unsigned short* wo_t   = (unsigned short*)(ws + 50331648);      // 4096x4096 bf16
  unsigned short* xb     = (unsigned short*)(ws + 83886080);      // 2048x4096 bf16
  unsigned short* Qr     = (unsigned short*)(ws + 100663296);     // 2*32*1024*128 bf16
  unsigned short* Kr     = (unsigned short*)(ws + 117440512);     // 2*8*1024*128 bf16
  unsigned short* Vt     = (unsigned short*)(ws + 121634816);     // 2*8*128*1024 bf16
  unsigned short* attn   = (unsigned short*)(ws + 125829120);     // 2048x4096 bf16

  k_prep<<<18432, 256, 0, stream>>>(x, w_qkv, w_o, xb, wqkv_t, wo_t);
  k_gemm<1><<<dim3(16, 48), 256, 0, stream>>>(xb, wqkv_t, nullptr, Qr, Kr, Vt, cosT, sinT,
                                              2048, 6144, 4096);
  k_attn<<<dim3(8, 32, 2), 256, 0, stream>>>(Qr, Kr, Vt, attn);
  k_gemm<0><<<dim3(16, 32), 256, 0, stream>>>(attn, wo_t, (float*)d_out, nullptr, nullptr, nullptr,
                                              nullptr, nullptr, 2048, 4096, 4096);
}